// Round 2
// baseline (1038.289 us; speedup 1.0000x reference)
//
#include <hip/hip_runtime.h>
#include <hip/hip_bf16.h>

// ---------- types ----------
typedef __attribute__((ext_vector_type(8))) short bf16x8;  // 8 bf16 in 4 VGPRs
typedef __attribute__((ext_vector_type(4))) float f32x4;

__device__ __forceinline__ unsigned short f2bf(float f) {
  union { float f; unsigned u; } v; v.f = f;
  unsigned r = v.u + 0x7FFFu + ((v.u >> 16) & 1u);  // RNE
  return (unsigned short)(r >> 16);
}

__device__ __forceinline__ void gl_lds16(const void* g, void* l) {
  __builtin_amdgcn_global_load_lds(
      (__attribute__((address_space(1))) void*)(g),
      (__attribute__((address_space(3))) void*)(l), 16, 0, 0);
}

// ---------- f32 -> bf16 convert (vectorized) ----------
__global__ __launch_bounds__(256) void k_convert(const float* __restrict__ in,
                                                 unsigned short* __restrict__ out,
                                                 int n8) {
  int i = blockIdx.x * 256 + threadIdx.x;
  if (i >= n8) return;
  const float4* ip = (const float4*)in;
  float4 v0 = ip[2 * i], v1 = ip[2 * i + 1];
  ushort4 o0 = make_ushort4(f2bf(v0.x), f2bf(v0.y), f2bf(v0.z), f2bf(v0.w));
  ushort4 o1 = make_ushort4(f2bf(v1.x), f2bf(v1.y), f2bf(v1.z), f2bf(v1.w));
  ((ushort4*)out)[2 * i] = o0;
  ((ushort4*)out)[2 * i + 1] = o1;
}

// ---------- batched transpose: in [R][C] f32 -> out [C][R] (f32 or bf16) ----------
template <typename OutT>
__global__ __launch_bounds__(256) void k_transpose(const float* __restrict__ in,
                                                   OutT* __restrict__ out,
                                                   int R, int C,
                                                   long inStride, long outStride) {
  __shared__ float tile[64][65];
  const float* ib = in + (long)blockIdx.z * inStride;
  OutT* ob = out + (long)blockIdx.z * outStride;
  int tc = blockIdx.x * 64;  // column tile of input (C dim)
  int tr = blockIdx.y * 64;  // row tile of input (R dim)
  int t = threadIdx.x;
  int lr = t >> 4;         // 0..15
  int lc = (t & 15) * 4;   // 0..60
#pragma unroll
  for (int rr = 0; rr < 64; rr += 16) {
    float4 v = *(const float4*)&ib[(long)(tr + rr + lr) * C + tc + lc];
    tile[rr + lr][lc + 0] = v.x;
    tile[rr + lr][lc + 1] = v.y;
    tile[rr + lr][lc + 2] = v.z;
    tile[rr + lr][lc + 3] = v.w;
  }
  __syncthreads();
  // out[(tc + i)][tr + j] = tile[j][i]
#pragma unroll
  for (int ii = 0; ii < 64; ii += 16) {
    int i = ii + lr;
    if constexpr (sizeof(OutT) == 2) {
      ushort4 w = make_ushort4(f2bf(tile[lc + 0][i]), f2bf(tile[lc + 1][i]),
                               f2bf(tile[lc + 2][i]), f2bf(tile[lc + 3][i]));
      *(ushort4*)&ob[(long)(tc + i) * R + tr + lc] = w;
    } else {
      float4 w = make_float4(tile[lc + 0][i], tile[lc + 1][i],
                             tile[lc + 2][i], tile[lc + 3][i]);
      *(float4*)&ob[(long)(tc + i) * R + tr + lc] = w;
    }
  }
}

// ---------- row softmax: E [rows][1024] f32 -> P bf16 ----------
__global__ __launch_bounds__(256) void k_softmax(const float* __restrict__ E,
                                                 unsigned short* __restrict__ P) {
  long row = blockIdx.x;
  const float* e = E + row * 1024;
  int t = threadIdx.x;
  float4 v = *(const float4*)&e[t * 4];
  float m = fmaxf(fmaxf(v.x, v.y), fmaxf(v.z, v.w));
#pragma unroll
  for (int o = 32; o; o >>= 1) m = fmaxf(m, __shfl_xor(m, o));
  __shared__ float red[4];
  __shared__ float red2[4];
  int wid = t >> 6;
  if ((t & 63) == 0) red[wid] = m;
  __syncthreads();
  m = fmaxf(fmaxf(red[0], red[1]), fmaxf(red[2], red[3]));
  float p0 = __expf(v.x - m), p1 = __expf(v.y - m);
  float p2 = __expf(v.z - m), p3 = __expf(v.w - m);
  float s = p0 + p1 + p2 + p3;
#pragma unroll
  for (int o = 32; o; o >>= 1) s += __shfl_xor(s, o);
  if ((t & 63) == 0) red2[wid] = s;
  __syncthreads();
  s = red2[0] + red2[1] + red2[2] + red2[3];
  float inv = 1.0f / s;
  ushort4 o4 = make_ushort4(f2bf(p0 * inv), f2bf(p1 * inv),
                            f2bf(p2 * inv), f2bf(p3 * inv));
  *(ushort4*)&P[row * 1024 + t * 4] = o4;
}

// ---------- column softmax: E [1024][1024] f32 per batch -> P[i][j] = exp(E[i][j]-m_j)/s_j ----------
// Each block: 64 columns of one batch; 256 threads = 4 row-phases x 64 cols.
__global__ __launch_bounds__(256) void k_colsoftmax(const float* __restrict__ E,
                                                    unsigned short* __restrict__ P) {
  const long base = (long)blockIdx.y * 1048576L;
  const float* e = E + base;
  unsigned short* p = P + base;
  const int t = threadIdx.x;
  const int cl = t & 63;
  const int c = blockIdx.x * 64 + cl;
  const int r0 = t >> 6;  // 0..3
  float m = -3.4e38f;
  for (int r = r0; r < 1024; r += 4) m = fmaxf(m, e[(long)r * 1024 + c]);
  __shared__ float red[4][64];
  red[r0][cl] = m;
  __syncthreads();
  m = fmaxf(fmaxf(red[0][cl], red[1][cl]), fmaxf(red[2][cl], red[3][cl]));
  float s = 0.f;
  for (int r = r0; r < 1024; r += 4) s += __expf(e[(long)r * 1024 + c] - m);
  __syncthreads();
  red[r0][cl] = s;
  __syncthreads();
  s = red[0][cl] + red[1][cl] + red[2][cl] + red[3][cl];
  float inv = 1.0f / s;
  for (int r = r0; r < 1024; r += 4)
    p[(long)r * 1024 + c] = f2bf(__expf(e[(long)r * 1024 + c] - m) * inv);
}

// ---------- GEMM-BT: C[m,n] = sum_k A[m,k] * Bt[n,k]  (both bf16, K-contiguous) ----------
// 128x128 tile, BK=32, 256 threads (4 waves, 2x2), mfma 16x16x32 bf16.
template <bool BIAS_RELU, bool OUT_BF16>
__global__ __launch_bounds__(256, 2) void k_gemm_bt(
    const unsigned short* __restrict__ A, long lda, long aBatch,
    const unsigned short* __restrict__ Bt, long ldb, long bBatch,
    void* __restrict__ C, long ldc, long cBatch,
    const float* __restrict__ bias, int K) {
  __shared__ unsigned short As[128 * 32];
  __shared__ unsigned short Bs[128 * 32];
  const int t = threadIdx.x;
  const int w = t >> 6, l = t & 63;
  const int lr = l & 15, lh = l >> 4;
  const int wr = w >> 1, wc = w & 1;
  const long m0 = (long)blockIdx.y * 128;
  const long n0 = (long)blockIdx.x * 128;
  const unsigned short* Ab = A + (long)blockIdx.z * aBatch;
  const unsigned short* Bb = Bt + (long)blockIdx.z * bBatch;

  // staging: each wave covers 2 chunks (16 rows x 32 cols each) of A and B
  const int ca0 = w * 2, ca1 = w * 2 + 1;
  const int srow = l >> 2;       // 0..15
  const int scol = (l & 3) * 8;  // in shorts
  const unsigned short* ag0 = Ab + (m0 + ca0 * 16 + srow) * lda + scol;
  const unsigned short* ag1 = Ab + (m0 + ca1 * 16 + srow) * lda + scol;
  const unsigned short* bg0 = Bb + (n0 + ca0 * 16 + srow) * ldb + scol;
  const unsigned short* bg1 = Bb + (n0 + ca1 * 16 + srow) * ldb + scol;
  unsigned short* al0 = &As[ca0 * 512];
  unsigned short* al1 = &As[ca1 * 512];
  unsigned short* bl0 = &Bs[ca0 * 512];
  unsigned short* bl1 = &Bs[ca1 * 512];

  f32x4 acc[4][4];
#pragma unroll
  for (int i = 0; i < 4; ++i)
#pragma unroll
    for (int j = 0; j < 4; ++j) acc[i][j] = (f32x4){0.f, 0.f, 0.f, 0.f};

  for (int k0 = 0; k0 < K; k0 += 32) {
    gl_lds16(ag0 + k0, al0);
    gl_lds16(ag1 + k0, al1);
    gl_lds16(bg0 + k0, bl0);
    gl_lds16(bg1 + k0, bl1);
    __syncthreads();
    bf16x8 af[4], bfr[4];
#pragma unroll
    for (int m = 0; m < 4; ++m)
      af[m] = *(const bf16x8*)&As[(wr * 64 + m * 16 + lr) * 32 + lh * 8];
#pragma unroll
    for (int n = 0; n < 4; ++n)
      bfr[n] = *(const bf16x8*)&Bs[(wc * 64 + n * 16 + lr) * 32 + lh * 8];
#pragma unroll
    for (int m = 0; m < 4; ++m)
#pragma unroll
      for (int n = 0; n < 4; ++n)
        acc[m][n] = __builtin_amdgcn_mfma_f32_16x16x32_bf16(af[m], bfr[n], acc[m][n], 0, 0, 0);
    __syncthreads();
  }

  const long crow = m0 + wr * 64;
  const long ccol = n0 + wc * 64;
#pragma unroll
  for (int n = 0; n < 4; ++n) {
    const long col = ccol + n * 16 + lr;
    float bv = 0.f;
    if constexpr (BIAS_RELU) bv = bias[col];
#pragma unroll
    for (int m = 0; m < 4; ++m) {
      f32x4 v = acc[m][n];
#pragma unroll
      for (int r = 0; r < 4; ++r) {
        const long rrow = crow + m * 16 + lh * 4 + r;
        float x = v[r];
        if constexpr (BIAS_RELU) x = fmaxf(x + bv, 0.f);
        if constexpr (OUT_BF16)
          ((unsigned short*)C)[(long)blockIdx.z * cBatch + rrow * ldc + col] = f2bf(x);
        else
          ((float*)C)[(long)blockIdx.z * cBatch + rrow * ldc + col] = x;
      }
    }
  }
}

// ---------- launcher ----------
extern "C" void kernel_launch(void* const* d_in, const int* in_sizes, int n_in,
                              void* d_out, int out_size, void* d_ws, size_t ws_size,
                              hipStream_t stream) {
  const float* A_in = (const float*)d_in[0];  // [32,1024,768]
  const float* B_in = (const float*)d_in[1];  // [32,1024,768]
  const float* W1 = (const float*)d_in[2];    // [768,1024]
  const float* b1 = (const float*)d_in[3];    // [1024]
  const float* W2 = (const float*)d_in[4];    // [1024,1024]
  const float* b2 = (const float*)d_in[5];    // [1024]

  char* ws = (char*)d_ws;
  // region layout (bytes):
  unsigned short* Xbf  = (unsigned short*)(ws + 0L);           // 65536x768 bf16 (96MB); later P
  unsigned short* H    = (unsigned short*)(ws + 100663296L);   // 65536x1024 bf16 (128MB)
  unsigned short* F    = (unsigned short*)(ws + 234881024L);   // 65536x1024 bf16 (128MB); later P2
  unsigned short* BinT = (unsigned short*)(ws + 369098752L);   // 32x768x1024 bf16 (48MB)
  unsigned short* W1T  = (unsigned short*)(ws + 419430400L);   // 1024x768 bf16
  unsigned short* W2T  = (unsigned short*)(ws + 421003264L);   // 1024x1024 bf16
  unsigned short* P    = (unsigned short*)(ws + 0L);           // 32x1024x1024 bf16 (64MB)
  unsigned short* P2   = (unsigned short*)(ws + 234881024L);   // 32x1024x1024 bf16 (64MB)
  float* E  = (float*)d_out;                                   // 32x1024x1024 f32 (134MB, fits in 201MB out)
  float* beta = (float*)d_out;
  float* alpha = (float*)d_out + 25165824L;

  // 1) converts / transposes of inputs
  k_convert<<<12288, 256, 0, stream>>>(A_in, Xbf, 3145728);
  k_convert<<<12288, 256, 0, stream>>>(B_in, Xbf + 25165824L, 3145728);
  k_transpose<unsigned short><<<dim3(16, 12, 1), 256, 0, stream>>>(W1, W1T, 768, 1024, 0, 0);
  k_transpose<unsigned short><<<dim3(16, 16, 1), 256, 0, stream>>>(W2, W2T, 1024, 1024, 0, 0);
  k_transpose<unsigned short><<<dim3(12, 16, 32), 256, 0, stream>>>(B_in, BinT, 1024, 768, 786432L, 786432L);

  // 2) MLP: H = relu(X@W1+b1); F = relu(H@W2+b2)   (X rows: A then B)
  k_gemm_bt<true, true><<<dim3(8, 512, 1), 256, 0, stream>>>(
      Xbf, 768, 0, W1T, 768, 0, (void*)H, 1024, 0, b1, 768);
  k_gemm_bt<true, true><<<dim3(8, 512, 1), 256, 0, stream>>>(
      H, 1024, 0, W2T, 1024, 0, (void*)F, 1024, 0, b2, 1024);

  // 3) E[b] = fA[b] @ fB[b]^T  (f32 out, into d_out as scratch)
  k_gemm_bt<false, false><<<dim3(8, 8, 32), 256, 0, stream>>>(
      F, 1024, 1048576L, F + 33554432L, 1024, 1048576L, (void*)E, 1024, 1048576L, nullptr, 1024);

  // 4) row softmax -> P (for beta); column softmax -> P2 (for alpha)
  k_softmax<<<32768, 256, 0, stream>>>(E, P);
  k_colsoftmax<<<dim3(16, 32), 256, 0, stream>>>(E, P2);

  // 5) beta = P @ B ; alpha = P2 @ B   (B as BinT, NT-form GEMM)
  k_gemm_bt<false, false><<<dim3(6, 8, 32), 256, 0, stream>>>(
      P, 1024, 1048576L, BinT, 1024, 786432L, (void*)beta, 768, 786432L, nullptr, 1024);
  k_gemm_bt<false, false><<<dim3(6, 8, 32), 256, 0, stream>>>(
      P2, 1024, 1048576L, BinT, 1024, 786432L, (void*)alpha, 768, 786432L, nullptr, 1024);
}

// Round 3
// 895.928 us; speedup vs baseline: 1.1589x; 1.1589x over previous
//
#include <hip/hip_runtime.h>
#include <hip/hip_bf16.h>

// ---------- types ----------
typedef __attribute__((ext_vector_type(8))) short bf16x8;  // 8 bf16 in 4 VGPRs
typedef __attribute__((ext_vector_type(4))) float f32x4;

__device__ __forceinline__ unsigned short f2bf(float f) {
  union { float f; unsigned u; } v; v.f = f;
  unsigned r = v.u + 0x7FFFu + ((v.u >> 16) & 1u);  // RNE
  return (unsigned short)(r >> 16);
}

__device__ __forceinline__ void gl_lds16(const void* g, void* l) {
  __builtin_amdgcn_global_load_lds(
      (__attribute__((address_space(1))) void*)(g),
      (__attribute__((address_space(3))) void*)(l), 16, 0, 0);
}

// ---------- f32 -> bf16 convert (vectorized) ----------
__global__ __launch_bounds__(256) void k_convert(const float* __restrict__ in,
                                                 unsigned short* __restrict__ out,
                                                 int n8) {
  int i = blockIdx.x * 256 + threadIdx.x;
  if (i >= n8) return;
  const float4* ip = (const float4*)in;
  float4 v0 = ip[2 * i], v1 = ip[2 * i + 1];
  ushort4 o0 = make_ushort4(f2bf(v0.x), f2bf(v0.y), f2bf(v0.z), f2bf(v0.w));
  ushort4 o1 = make_ushort4(f2bf(v1.x), f2bf(v1.y), f2bf(v1.z), f2bf(v1.w));
  ((ushort4*)out)[2 * i] = o0;
  ((ushort4*)out)[2 * i + 1] = o1;
}

// ---------- batched transpose: in [R][C] f32 -> out [C][R] (f32 or bf16) ----------
template <typename OutT>
__global__ __launch_bounds__(256) void k_transpose(const float* __restrict__ in,
                                                   OutT* __restrict__ out,
                                                   int R, int C,
                                                   long inStride, long outStride) {
  __shared__ float tile[64][65];
  const float* ib = in + (long)blockIdx.z * inStride;
  OutT* ob = out + (long)blockIdx.z * outStride;
  int tc = blockIdx.x * 64;  // column tile of input (C dim)
  int tr = blockIdx.y * 64;  // row tile of input (R dim)
  int t = threadIdx.x;
  int lr = t >> 4;         // 0..15
  int lc = (t & 15) * 4;   // 0..60
#pragma unroll
  for (int rr = 0; rr < 64; rr += 16) {
    float4 v = *(const float4*)&ib[(long)(tr + rr + lr) * C + tc + lc];
    tile[rr + lr][lc + 0] = v.x;
    tile[rr + lr][lc + 1] = v.y;
    tile[rr + lr][lc + 2] = v.z;
    tile[rr + lr][lc + 3] = v.w;
  }
  __syncthreads();
  // out[(tc + i)][tr + j] = tile[j][i]
#pragma unroll
  for (int ii = 0; ii < 64; ii += 16) {
    int i = ii + lr;
    if constexpr (sizeof(OutT) == 2) {
      ushort4 w = make_ushort4(f2bf(tile[lc + 0][i]), f2bf(tile[lc + 1][i]),
                               f2bf(tile[lc + 2][i]), f2bf(tile[lc + 3][i]));
      *(ushort4*)&ob[(long)(tc + i) * R + tr + lc] = w;
    } else {
      float4 w = make_float4(tile[lc + 0][i], tile[lc + 1][i],
                             tile[lc + 2][i], tile[lc + 3][i]);
      *(float4*)&ob[(long)(tc + i) * R + tr + lc] = w;
    }
  }
}

// ---------- phase 1: partial column stats (online max/sumexp over 128-row chunk) ----------
// grid: (8 row-chunks, 32 batches); 256 threads; thread t owns cols 4t..4t+3.
__global__ __launch_bounds__(256) void k_colstats(const float* __restrict__ E,
                                                  float* __restrict__ colMp,
                                                  float* __restrict__ colSp) {
  const float* e = E + (long)blockIdx.y * 1048576L + (long)blockIdx.x * 131072L +
                   threadIdx.x * 4;
  float m0 = -3.4e38f, m1 = -3.4e38f, m2 = -3.4e38f, m3 = -3.4e38f;
  float s0 = 0.f, s1 = 0.f, s2 = 0.f, s3 = 0.f;
  for (int r = 0; r < 128; ++r) {
    float4 v = *(const float4*)(e + (long)r * 1024);
    float n0 = fmaxf(m0, v.x); s0 = s0 * __expf(m0 - n0) + __expf(v.x - n0); m0 = n0;
    float n1 = fmaxf(m1, v.y); s1 = s1 * __expf(m1 - n1) + __expf(v.y - n1); m1 = n1;
    float n2 = fmaxf(m2, v.z); s2 = s2 * __expf(m2 - n2) + __expf(v.z - n2); m2 = n2;
    float n3 = fmaxf(m3, v.w); s3 = s3 * __expf(m3 - n3) + __expf(v.w - n3); m3 = n3;
  }
  long o = ((long)blockIdx.y * 8 + blockIdx.x) * 1024 + threadIdx.x * 4;
  *(float4*)&colMp[o] = make_float4(m0, m1, m2, m3);
  *(float4*)&colSp[o] = make_float4(s0, s1, s2, s3);
}

// ---------- phase 2: combine 8 chunk stats per column ----------
__global__ __launch_bounds__(256) void k_colcombine(const float* __restrict__ colMp,
                                                    const float* __restrict__ colSp,
                                                    float* __restrict__ colM,
                                                    float* __restrict__ colIS) {
  int idx = blockIdx.x * 256 + threadIdx.x;  // 0..32767
  int b = idx >> 10, c = idx & 1023;
  float m = -3.4e38f;
  float mc[8], sc[8];
#pragma unroll
  for (int k = 0; k < 8; ++k) {
    mc[k] = colMp[((long)b * 8 + k) * 1024 + c];
    sc[k] = colSp[((long)b * 8 + k) * 1024 + c];
    m = fmaxf(m, mc[k]);
  }
  float s = 0.f;
#pragma unroll
  for (int k = 0; k < 8; ++k) s += sc[k] * __expf(mc[k] - m);
  colM[idx] = m;
  colIS[idx] = 1.0f / s;
}

// ---------- phase 3: fused row softmax -> P, column-softmax apply -> P2 ----------
// block = one global row (b*1024 + i); 256 threads; thread t owns cols 4t..4t+3.
__global__ __launch_bounds__(256) void k_softmax(const float* __restrict__ E,
                                                 unsigned short* __restrict__ P,
                                                 unsigned short* __restrict__ P2,
                                                 const float* __restrict__ colM,
                                                 const float* __restrict__ colIS) {
  long row = blockIdx.x;
  const float* e = E + row * 1024;
  int t = threadIdx.x;
  float4 v = *(const float4*)&e[t * 4];
  float m = fmaxf(fmaxf(v.x, v.y), fmaxf(v.z, v.w));
#pragma unroll
  for (int o = 32; o; o >>= 1) m = fmaxf(m, __shfl_xor(m, o));
  __shared__ float red[4];
  __shared__ float red2[4];
  int wid = t >> 6;
  if ((t & 63) == 0) red[wid] = m;
  __syncthreads();
  m = fmaxf(fmaxf(red[0], red[1]), fmaxf(red[2], red[3]));
  float p0 = __expf(v.x - m), p1 = __expf(v.y - m);
  float p2 = __expf(v.z - m), p3 = __expf(v.w - m);
  float s = p0 + p1 + p2 + p3;
#pragma unroll
  for (int o = 32; o; o >>= 1) s += __shfl_xor(s, o);
  if ((t & 63) == 0) red2[wid] = s;
  __syncthreads();
  s = red2[0] + red2[1] + red2[2] + red2[3];
  float inv = 1.0f / s;
  *(ushort4*)&P[row * 1024 + t * 4] =
      make_ushort4(f2bf(p0 * inv), f2bf(p1 * inv), f2bf(p2 * inv), f2bf(p3 * inv));
  // column-softmax apply using precomputed per-column stats
  long cb = (row >> 10) * 1024 + t * 4;
  float4 cm = *(const float4*)&colM[cb];
  float4 ci = *(const float4*)&colIS[cb];
  *(ushort4*)&P2[row * 1024 + t * 4] =
      make_ushort4(f2bf(__expf(v.x - cm.x) * ci.x), f2bf(__expf(v.y - cm.y) * ci.y),
                   f2bf(__expf(v.z - cm.z) * ci.z), f2bf(__expf(v.w - cm.w) * ci.w));
}

// ---------- GEMM-BT: C[m,n] = sum_k A[m,k] * Bt[n,k]  (both bf16, K-contiguous) ----------
// 128x128 tile, BK=32, 256 threads (4 waves, 2x2), mfma 16x16x32 bf16.
template <bool BIAS_RELU, bool OUT_BF16>
__global__ __launch_bounds__(256, 2) void k_gemm_bt(
    const unsigned short* __restrict__ A, long lda, long aBatch,
    const unsigned short* __restrict__ Bt, long ldb, long bBatch,
    void* __restrict__ C, long ldc, long cBatch,
    const float* __restrict__ bias, int K) {
  __shared__ unsigned short As[128 * 32];
  __shared__ unsigned short Bs[128 * 32];
  const int t = threadIdx.x;
  const int w = t >> 6, l = t & 63;
  const int lr = l & 15, lh = l >> 4;
  const int wr = w >> 1, wc = w & 1;
  const long m0 = (long)blockIdx.y * 128;
  const long n0 = (long)blockIdx.x * 128;
  const unsigned short* Ab = A + (long)blockIdx.z * aBatch;
  const unsigned short* Bb = Bt + (long)blockIdx.z * bBatch;

  // staging: each wave covers 2 chunks (16 rows x 32 cols each) of A and B
  const int ca0 = w * 2, ca1 = w * 2 + 1;
  const int srow = l >> 2;       // 0..15
  const int scol = (l & 3) * 8;  // in shorts
  const unsigned short* ag0 = Ab + (m0 + ca0 * 16 + srow) * lda + scol;
  const unsigned short* ag1 = Ab + (m0 + ca1 * 16 + srow) * lda + scol;
  const unsigned short* bg0 = Bb + (n0 + ca0 * 16 + srow) * ldb + scol;
  const unsigned short* bg1 = Bb + (n0 + ca1 * 16 + srow) * ldb + scol;
  unsigned short* al0 = &As[ca0 * 512];
  unsigned short* al1 = &As[ca1 * 512];
  unsigned short* bl0 = &Bs[ca0 * 512];
  unsigned short* bl1 = &Bs[ca1 * 512];

  f32x4 acc[4][4];
#pragma unroll
  for (int i = 0; i < 4; ++i)
#pragma unroll
    for (int j = 0; j < 4; ++j) acc[i][j] = (f32x4){0.f, 0.f, 0.f, 0.f};

  for (int k0 = 0; k0 < K; k0 += 32) {
    gl_lds16(ag0 + k0, al0);
    gl_lds16(ag1 + k0, al1);
    gl_lds16(bg0 + k0, bl0);
    gl_lds16(bg1 + k0, bl1);
    __syncthreads();
    bf16x8 af[4], bfr[4];
#pragma unroll
    for (int m = 0; m < 4; ++m)
      af[m] = *(const bf16x8*)&As[(wr * 64 + m * 16 + lr) * 32 + lh * 8];
#pragma unroll
    for (int n = 0; n < 4; ++n)
      bfr[n] = *(const bf16x8*)&Bs[(wc * 64 + n * 16 + lr) * 32 + lh * 8];
#pragma unroll
    for (int m = 0; m < 4; ++m)
#pragma unroll
      for (int n = 0; n < 4; ++n)
        acc[m][n] = __builtin_amdgcn_mfma_f32_16x16x32_bf16(af[m], bfr[n], acc[m][n], 0, 0, 0);
    __syncthreads();
  }

  const long crow = m0 + wr * 64;
  const long ccol = n0 + wc * 64;
#pragma unroll
  for (int n = 0; n < 4; ++n) {
    const long col = ccol + n * 16 + lr;
    float bv = 0.f;
    if constexpr (BIAS_RELU) bv = bias[col];
#pragma unroll
    for (int m = 0; m < 4; ++m) {
      f32x4 v = acc[m][n];
#pragma unroll
      for (int r = 0; r < 4; ++r) {
        const long rrow = crow + m * 16 + lh * 4 + r;
        float x = v[r];
        if constexpr (BIAS_RELU) x = fmaxf(x + bv, 0.f);
        if constexpr (OUT_BF16)
          ((unsigned short*)C)[(long)blockIdx.z * cBatch + rrow * ldc + col] = f2bf(x);
        else
          ((float*)C)[(long)blockIdx.z * cBatch + rrow * ldc + col] = x;
      }
    }
  }
}

// ---------- launcher ----------
extern "C" void kernel_launch(void* const* d_in, const int* in_sizes, int n_in,
                              void* d_out, int out_size, void* d_ws, size_t ws_size,
                              hipStream_t stream) {
  const float* A_in = (const float*)d_in[0];  // [32,1024,768]
  const float* B_in = (const float*)d_in[1];  // [32,1024,768]
  const float* W1 = (const float*)d_in[2];    // [768,1024]
  const float* b1 = (const float*)d_in[3];    // [1024]
  const float* W2 = (const float*)d_in[4];    // [1024,1024]
  const float* b2 = (const float*)d_in[5];    // [1024]

  char* ws = (char*)d_ws;
  // region layout (bytes):
  unsigned short* Xbf  = (unsigned short*)(ws + 0L);           // 65536x768 bf16 (96MB); later P
  unsigned short* H    = (unsigned short*)(ws + 100663296L);   // 65536x1024 bf16 (128MB); later stats
  unsigned short* F    = (unsigned short*)(ws + 234881024L);   // 65536x1024 bf16 (128MB); later P2
  unsigned short* BinT = (unsigned short*)(ws + 369098752L);   // 32x768x1024 bf16 (48MB)
  unsigned short* W1T  = (unsigned short*)(ws + 419430400L);   // 1024x768 bf16
  unsigned short* W2T  = (unsigned short*)(ws + 421003264L);   // 1024x1024 bf16
  unsigned short* P    = (unsigned short*)(ws + 0L);           // 32x1024x1024 bf16 (64MB)
  unsigned short* P2   = (unsigned short*)(ws + 234881024L);   // 32x1024x1024 bf16 (64MB)
  // column-softmax stats live in the (free after GEMM2) H region:
  float* colMp = (float*)(ws + 100663296L);                    // [32][8][1024] f32 (1MB)
  float* colSp = (float*)(ws + 100663296L + 1048576L);         // [32][8][1024] f32 (1MB)
  float* colM  = (float*)(ws + 100663296L + 2097152L);         // [32][1024] f32
  float* colIS = (float*)(ws + 100663296L + 2228224L);         // [32][1024] f32
  float* E  = (float*)d_out;                                   // 32x1024x1024 f32 (134MB)
  float* beta = (float*)d_out;
  float* alpha = (float*)d_out + 25165824L;

  // 1) converts / transposes of inputs
  k_convert<<<12288, 256, 0, stream>>>(A_in, Xbf, 3145728);
  k_convert<<<12288, 256, 0, stream>>>(B_in, Xbf + 25165824L, 3145728);
  k_transpose<unsigned short><<<dim3(16, 12, 1), 256, 0, stream>>>(W1, W1T, 768, 1024, 0, 0);
  k_transpose<unsigned short><<<dim3(16, 16, 1), 256, 0, stream>>>(W2, W2T, 1024, 1024, 0, 0);
  k_transpose<unsigned short><<<dim3(12, 16, 32), 256, 0, stream>>>(B_in, BinT, 1024, 768, 786432L, 786432L);

  // 2) MLP: H = relu(X@W1+b1); F = relu(H@W2+b2)   (X rows: A then B)
  k_gemm_bt<true, true><<<dim3(8, 512, 1), 256, 0, stream>>>(
      Xbf, 768, 0, W1T, 768, 0, (void*)H, 1024, 0, b1, 768);
  k_gemm_bt<true, true><<<dim3(8, 512, 1), 256, 0, stream>>>(
      H, 1024, 0, W2T, 1024, 0, (void*)F, 1024, 0, b2, 1024);

  // 3) E[b] = fA[b] @ fB[b]^T  (f32 out, into d_out as scratch)
  k_gemm_bt<false, false><<<dim3(8, 8, 32), 256, 0, stream>>>(
      F, 1024, 1048576L, F + 33554432L, 1024, 1048576L, (void*)E, 1024, 1048576L, nullptr, 1024);

  // 4) column stats (streaming), combine, then fused row-softmax + col-apply
  k_colstats<<<dim3(8, 32), 256, 0, stream>>>(E, colMp, colSp);
  k_colcombine<<<128, 256, 0, stream>>>(colMp, colSp, colM, colIS);
  k_softmax<<<32768, 256, 0, stream>>>(E, P, P2, colM, colIS);

  // 5) beta = P @ B ; alpha = P2 @ B   (B as BinT, NT-form GEMM)
  k_gemm_bt<false, false><<<dim3(6, 8, 32), 256, 0, stream>>>(
      P, 1024, 1048576L, BinT, 1024, 786432L, (void*)beta, 768, 786432L, nullptr, 1024);
  k_gemm_bt<false, false><<<dim3(6, 8, 32), 256, 0, stream>>>(
      P2, 1024, 1048576L, BinT, 1024, 786432L, (void*)alpha, 768, 786432L, nullptr, 1024);
}

// Round 4
// 769.243 us; speedup vs baseline: 1.3498x; 1.1647x over previous
//
#include <hip/hip_runtime.h>
#include <hip/hip_bf16.h>

// ---------- types ----------
typedef __attribute__((ext_vector_type(8))) short bf16x8;  // 8 bf16 in 4 VGPRs
typedef __attribute__((ext_vector_type(4))) float f32x4;

__device__ __forceinline__ unsigned short f2bf(float f) {
  union { float f; unsigned u; } v; v.f = f;
  unsigned r = v.u + 0x7FFFu + ((v.u >> 16) & 1u);  // RNE
  return (unsigned short)(r >> 16);
}

__device__ __forceinline__ void gl_lds16(const void* g, void* l) {
  __builtin_amdgcn_global_load_lds(
      (__attribute__((address_space(1))) void*)(g),
      (__attribute__((address_space(3))) void*)(l), 16, 0, 0);
}

// ---------- f32 -> bf16 convert (vectorized) ----------
__global__ __launch_bounds__(256) void k_convert(const float* __restrict__ in,
                                                 unsigned short* __restrict__ out,
                                                 int n8) {
  int i = blockIdx.x * 256 + threadIdx.x;
  if (i >= n8) return;
  const float4* ip = (const float4*)in;
  float4 v0 = ip[2 * i], v1 = ip[2 * i + 1];
  ushort4 o0 = make_ushort4(f2bf(v0.x), f2bf(v0.y), f2bf(v0.z), f2bf(v0.w));
  ushort4 o1 = make_ushort4(f2bf(v1.x), f2bf(v1.y), f2bf(v1.z), f2bf(v1.w));
  ((ushort4*)out)[2 * i] = o0;
  ((ushort4*)out)[2 * i + 1] = o1;
}

// ---------- batched transpose: in [R][C] f32 -> out [C][R] (f32 or bf16) ----------
template <typename OutT>
__global__ __launch_bounds__(256) void k_transpose(const float* __restrict__ in,
                                                   OutT* __restrict__ out,
                                                   int R, int C,
                                                   long inStride, long outStride) {
  __shared__ float tile[64][65];
  const float* ib = in + (long)blockIdx.z * inStride;
  OutT* ob = out + (long)blockIdx.z * outStride;
  int tc = blockIdx.x * 64;  // column tile of input (C dim)
  int tr = blockIdx.y * 64;  // row tile of input (R dim)
  int t = threadIdx.x;
  int lr = t >> 4;         // 0..15
  int lc = (t & 15) * 4;   // 0..60
#pragma unroll
  for (int rr = 0; rr < 64; rr += 16) {
    float4 v = *(const float4*)&ib[(long)(tr + rr + lr) * C + tc + lc];
    tile[rr + lr][lc + 0] = v.x;
    tile[rr + lr][lc + 1] = v.y;
    tile[rr + lr][lc + 2] = v.z;
    tile[rr + lr][lc + 3] = v.w;
  }
  __syncthreads();
  // out[(tc + i)][tr + j] = tile[j][i]
#pragma unroll
  for (int ii = 0; ii < 64; ii += 16) {
    int i = ii + lr;
    if constexpr (sizeof(OutT) == 2) {
      ushort4 w = make_ushort4(f2bf(tile[lc + 0][i]), f2bf(tile[lc + 1][i]),
                               f2bf(tile[lc + 2][i]), f2bf(tile[lc + 3][i]));
      *(ushort4*)&ob[(long)(tc + i) * R + tr + lc] = w;
    } else {
      float4 w = make_float4(tile[lc + 0][i], tile[lc + 1][i],
                             tile[lc + 2][i], tile[lc + 3][i]);
      *(float4*)&ob[(long)(tc + i) * R + tr + lc] = w;
    }
  }
}

// ---------- phase 1: partial column stats (online max/sumexp over 128-row chunk) ----------
__global__ __launch_bounds__(256) void k_colstats(const float* __restrict__ E,
                                                  float* __restrict__ colMp,
                                                  float* __restrict__ colSp) {
  const float* e = E + (long)blockIdx.y * 1048576L + (long)blockIdx.x * 131072L +
                   threadIdx.x * 4;
  float m0 = -3.4e38f, m1 = -3.4e38f, m2 = -3.4e38f, m3 = -3.4e38f;
  float s0 = 0.f, s1 = 0.f, s2 = 0.f, s3 = 0.f;
  for (int r = 0; r < 128; ++r) {
    float4 v = *(const float4*)(e + (long)r * 1024);
    float n0 = fmaxf(m0, v.x); s0 = s0 * __expf(m0 - n0) + __expf(v.x - n0); m0 = n0;
    float n1 = fmaxf(m1, v.y); s1 = s1 * __expf(m1 - n1) + __expf(v.y - n1); m1 = n1;
    float n2 = fmaxf(m2, v.z); s2 = s2 * __expf(m2 - n2) + __expf(v.z - n2); m2 = n2;
    float n3 = fmaxf(m3, v.w); s3 = s3 * __expf(m3 - n3) + __expf(v.w - n3); m3 = n3;
  }
  long o = ((long)blockIdx.y * 8 + blockIdx.x) * 1024 + threadIdx.x * 4;
  *(float4*)&colMp[o] = make_float4(m0, m1, m2, m3);
  *(float4*)&colSp[o] = make_float4(s0, s1, s2, s3);
}

// ---------- phase 2: combine 8 chunk stats per column ----------
__global__ __launch_bounds__(256) void k_colcombine(const float* __restrict__ colMp,
                                                    const float* __restrict__ colSp,
                                                    float* __restrict__ colM,
                                                    float* __restrict__ colIS) {
  int idx = blockIdx.x * 256 + threadIdx.x;  // 0..32767
  int b = idx >> 10, c = idx & 1023;
  float m = -3.4e38f;
  float mc[8], sc[8];
#pragma unroll
  for (int k = 0; k < 8; ++k) {
    mc[k] = colMp[((long)b * 8 + k) * 1024 + c];
    sc[k] = colSp[((long)b * 8 + k) * 1024 + c];
    m = fmaxf(m, mc[k]);
  }
  float s = 0.f;
#pragma unroll
  for (int k = 0; k < 8; ++k) s += sc[k] * __expf(mc[k] - m);
  colM[idx] = m;
  colIS[idx] = 1.0f / s;
}

// ---------- phase 3: fused row softmax -> P, column-softmax apply -> P2 ----------
__global__ __launch_bounds__(256) void k_softmax(const float* __restrict__ E,
                                                 unsigned short* __restrict__ P,
                                                 unsigned short* __restrict__ P2,
                                                 const float* __restrict__ colM,
                                                 const float* __restrict__ colIS) {
  long row = blockIdx.x;
  const float* e = E + row * 1024;
  int t = threadIdx.x;
  float4 v = *(const float4*)&e[t * 4];
  float m = fmaxf(fmaxf(v.x, v.y), fmaxf(v.z, v.w));
#pragma unroll
  for (int o = 32; o; o >>= 1) m = fmaxf(m, __shfl_xor(m, o));
  __shared__ float red[4];
  __shared__ float red2[4];
  int wid = t >> 6;
  if ((t & 63) == 0) red[wid] = m;
  __syncthreads();
  m = fmaxf(fmaxf(red[0], red[1]), fmaxf(red[2], red[3]));
  float p0 = __expf(v.x - m), p1 = __expf(v.y - m);
  float p2 = __expf(v.z - m), p3 = __expf(v.w - m);
  float s = p0 + p1 + p2 + p3;
#pragma unroll
  for (int o = 32; o; o >>= 1) s += __shfl_xor(s, o);
  if ((t & 63) == 0) red2[wid] = s;
  __syncthreads();
  s = red2[0] + red2[1] + red2[2] + red2[3];
  float inv = 1.0f / s;
  *(ushort4*)&P[row * 1024 + t * 4] =
      make_ushort4(f2bf(p0 * inv), f2bf(p1 * inv), f2bf(p2 * inv), f2bf(p3 * inv));
  long cb = (row >> 10) * 1024 + t * 4;
  float4 cm = *(const float4*)&colM[cb];
  float4 ci = *(const float4*)&colIS[cb];
  *(ushort4*)&P2[row * 1024 + t * 4] =
      make_ushort4(f2bf(__expf(v.x - cm.x) * ci.x), f2bf(__expf(v.y - cm.y) * ci.y),
                   f2bf(__expf(v.z - cm.z) * ci.z), f2bf(__expf(v.w - cm.w) * ci.w));
}

// ---------- GEMM-BT: C[m,n] = sum_k A[m,k] * Bt[n,k]  (both bf16, K-contiguous) ----------
// 128x128 tile, BK=32, 256 threads (4 waves, 2x2), mfma 16x16x32 bf16.
// XCD-affinity remap: hw-linear id -> logical tile so each XCD owns a contiguous
// run of logical tiles (A-tile shared by all N-tiles within one XCD's L2).
// LDS XOR-swizzle: source-side pre-swizzle (16B chunk ^ ((row>>1)&3)) + same XOR
// on ds_read slot; global_load_lds dest stays linear (rule: both-sides-or-neither).
template <bool BIAS_RELU, bool OUT_BF16>
__global__ __launch_bounds__(256, 4) void k_gemm_bt(
    const unsigned short* __restrict__ A, long lda, long aBatch,
    const unsigned short* __restrict__ Bt, long ldb, long bBatch,
    void* __restrict__ C, long ldc, long cBatch,
    const float* __restrict__ bias, int K) {
  __shared__ unsigned short As[128 * 32];
  __shared__ unsigned short Bs[128 * 32];
  const int t = threadIdx.x;
  const int w = t >> 6, l = t & 63;
  const int lr = l & 15, lh = l >> 4;
  const int wr = w >> 1, wc = w & 1;

  // XCD-affinity remap (grid size % 8 == 0 guaranteed by launcher)
  const int gx = gridDim.x, gy = gridDim.y;
  const int nwg = gx * gy * gridDim.z;
  const int hw = blockIdx.x + gx * (blockIdx.y + gy * blockIdx.z);
  const int q = nwg >> 3;
  const int logical = (hw & 7) * q + (hw >> 3);
  const int bx = logical % gx;
  const int rem = logical / gx;
  const int by = rem % gy;
  const int bz = rem / gy;

  const long m0 = (long)by * 128;
  const long n0 = (long)bx * 128;
  const unsigned short* Ab = A + (long)bz * aBatch;
  const unsigned short* Bb = Bt + (long)bz * bBatch;

  // staging: each wave covers 2 chunks (16 rows x 32 cols each) of A and B.
  const int ca0 = w * 2, ca1 = w * 2 + 1;
  const int srow = l >> 2;                          // 0..15
  const int sc16 = (l & 3) ^ ((srow >> 1) & 3);     // swizzled 16B-chunk of the row
  const int scol = sc16 * 8;                        // in shorts
  const unsigned short* ag0 = Ab + (m0 + ca0 * 16 + srow) * lda + scol;
  const unsigned short* ag1 = Ab + (m0 + ca1 * 16 + srow) * lda + scol;
  const unsigned short* bg0 = Bb + (n0 + ca0 * 16 + srow) * ldb + scol;
  const unsigned short* bg1 = Bb + (n0 + ca1 * 16 + srow) * ldb + scol;
  unsigned short* al0 = &As[ca0 * 512];
  unsigned short* al1 = &As[ca1 * 512];
  unsigned short* bl0 = &Bs[ca0 * 512];
  unsigned short* bl1 = &Bs[ca1 * 512];

  f32x4 acc[4][4];
#pragma unroll
  for (int i = 0; i < 4; ++i)
#pragma unroll
    for (int j = 0; j < 4; ++j) acc[i][j] = (f32x4){0.f, 0.f, 0.f, 0.f};

  const int rswz = ((lr >> 1) & 3) * 8;  // read-side XOR slot (in shorts)

  for (int k0 = 0; k0 < K; k0 += 32) {
    gl_lds16(ag0 + k0, al0);
    gl_lds16(ag1 + k0, al1);
    gl_lds16(bg0 + k0, bl0);
    gl_lds16(bg1 + k0, bl1);
    __syncthreads();
    bf16x8 af[4], bfr[4];
#pragma unroll
    for (int m = 0; m < 4; ++m)
      af[m] = *(const bf16x8*)&As[(wr * 64 + m * 16 + lr) * 32 + ((lh * 8) ^ rswz)];
#pragma unroll
    for (int n = 0; n < 4; ++n)
      bfr[n] = *(const bf16x8*)&Bs[(wc * 64 + n * 16 + lr) * 32 + ((lh * 8) ^ rswz)];
#pragma unroll
    for (int m = 0; m < 4; ++m)
#pragma unroll
      for (int n = 0; n < 4; ++n)
        acc[m][n] = __builtin_amdgcn_mfma_f32_16x16x32_bf16(af[m], bfr[n], acc[m][n], 0, 0, 0);
    __syncthreads();
  }

  const long crow = m0 + wr * 64;
  const long ccol = n0 + wc * 64;
#pragma unroll
  for (int n = 0; n < 4; ++n) {
    const long col = ccol + n * 16 + lr;
    float bv = 0.f;
    if constexpr (BIAS_RELU) bv = bias[col];
#pragma unroll
    for (int m = 0; m < 4; ++m) {
      f32x4 v = acc[m][n];
#pragma unroll
      for (int r = 0; r < 4; ++r) {
        const long rrow = crow + m * 16 + lh * 4 + r;
        float x = v[r];
        if constexpr (BIAS_RELU) x = fmaxf(x + bv, 0.f);
        if constexpr (OUT_BF16)
          ((unsigned short*)C)[(long)bz * cBatch + rrow * ldc + col] = f2bf(x);
        else
          ((float*)C)[(long)bz * cBatch + rrow * ldc + col] = x;
      }
    }
  }
}

// ---------- launcher ----------
extern "C" void kernel_launch(void* const* d_in, const int* in_sizes, int n_in,
                              void* d_out, int out_size, void* d_ws, size_t ws_size,
                              hipStream_t stream) {
  const float* A_in = (const float*)d_in[0];  // [32,1024,768]
  const float* B_in = (const float*)d_in[1];  // [32,1024,768]
  const float* W1 = (const float*)d_in[2];    // [768,1024]
  const float* b1 = (const float*)d_in[3];    // [1024]
  const float* W2 = (const float*)d_in[4];    // [1024,1024]
  const float* b2 = (const float*)d_in[5];    // [1024]

  char* ws = (char*)d_ws;
  unsigned short* Xbf  = (unsigned short*)(ws + 0L);           // 65536x768 bf16 (96MB); later P
  unsigned short* H    = (unsigned short*)(ws + 100663296L);   // 65536x1024 bf16 (128MB); later stats
  unsigned short* F    = (unsigned short*)(ws + 234881024L);   // 65536x1024 bf16 (128MB); later P2
  unsigned short* BinT = (unsigned short*)(ws + 369098752L);   // 32x768x1024 bf16 (48MB)
  unsigned short* W1T  = (unsigned short*)(ws + 419430400L);   // 1024x768 bf16
  unsigned short* W2T  = (unsigned short*)(ws + 421003264L);   // 1024x1024 bf16
  unsigned short* P    = (unsigned short*)(ws + 0L);           // 32x1024x1024 bf16 (64MB)
  unsigned short* P2   = (unsigned short*)(ws + 234881024L);   // 32x1024x1024 bf16 (64MB)
  float* colMp = (float*)(ws + 100663296L);                    // [32][8][1024] f32
  float* colSp = (float*)(ws + 100663296L + 1048576L);
  float* colM  = (float*)(ws + 100663296L + 2097152L);
  float* colIS = (float*)(ws + 100663296L + 2228224L);
  float* E  = (float*)d_out;                                   // 32x1024x1024 f32 (134MB)
  float* beta = (float*)d_out;
  float* alpha = (float*)d_out + 25165824L;

  // 1) converts / transposes of inputs
  k_convert<<<12288, 256, 0, stream>>>(A_in, Xbf, 3145728);
  k_convert<<<12288, 256, 0, stream>>>(B_in, Xbf + 25165824L, 3145728);
  k_transpose<unsigned short><<<dim3(16, 12, 1), 256, 0, stream>>>(W1, W1T, 768, 1024, 0, 0);
  k_transpose<unsigned short><<<dim3(16, 16, 1), 256, 0, stream>>>(W2, W2T, 1024, 1024, 0, 0);
  k_transpose<unsigned short><<<dim3(12, 16, 32), 256, 0, stream>>>(B_in, BinT, 1024, 768, 786432L, 786432L);

  // 2) MLP: H = relu(X@W1+b1); F = relu(H@W2+b2)   (X rows: A then B)
  k_gemm_bt<true, true><<<dim3(8, 512, 1), 256, 0, stream>>>(
      Xbf, 768, 0, W1T, 768, 0, (void*)H, 1024, 0, b1, 768);
  k_gemm_bt<true, true><<<dim3(8, 512, 1), 256, 0, stream>>>(
      H, 1024, 0, W2T, 1024, 0, (void*)F, 1024, 0, b2, 1024);

  // 3) E[b] = fA[b] @ fB[b]^T  (f32 out, into d_out as scratch)
  k_gemm_bt<false, false><<<dim3(8, 8, 32), 256, 0, stream>>>(
      F, 1024, 1048576L, F + 33554432L, 1024, 1048576L, (void*)E, 1024, 1048576L, nullptr, 1024);

  // 4) column stats (streaming), combine, then fused row-softmax + col-apply
  k_colstats<<<dim3(8, 32), 256, 0, stream>>>(E, colMp, colSp);
  k_colcombine<<<128, 256, 0, stream>>>(colMp, colSp, colM, colIS);
  k_softmax<<<32768, 256, 0, stream>>>(E, P, P2, colM, colIS);

  // 5) beta = P @ B ; alpha = P2 @ B   (B as BinT, NT-form GEMM)
  k_gemm_bt<false, false><<<dim3(6, 8, 32), 256, 0, stream>>>(
      P, 1024, 1048576L, BinT, 1024, 786432L, (void*)beta, 768, 786432L, nullptr, 1024);
  k_gemm_bt<false, false><<<dim3(6, 8, 32), 256, 0, stream>>>(
      P2, 1024, 1048576L, BinT, 1024, 786432L, (void*)alpha, 768, 786432L, nullptr, 1024);
}